// Round 8
// baseline (443.028 us; speedup 1.0000x reference)
//
#include <hip/hip_runtime.h>
#include <math.h>

constexpr int IMH = 2048, IMW = 2048, NB = 4;
constexpr int NPIX = NB * IMH * IMW;           // 16777216
constexpr unsigned KSEL = 8388607u;            // floor(0.5*(NPIX-1)) -> quantile 'lower'

__device__ __forceinline__ unsigned f2u(float f) {
    unsigned b = __float_as_uint(f);
    return (b & 0x80000000u) ? ~b : (b | 0x80000000u);
}

__device__ __forceinline__ void gauss7(float* a) {
    const double g0 = 0.8352702114112720;   // exp(-0.18)
    const double g1 = 0.9231163463866358;   // exp(-0.08)
    const double g2 = 0.9801986733067553;   // exp(-0.02)
    const double s = 2.0 * (g0 + g1 + g2) + 1.0;
    const double inv = 1.0 / s;
    a[0] = a[6] = (float)(g0 * inv);
    a[1] = a[5] = (float)(g1 * inv);
    a[2] = a[4] = (float)(g2 * inv);
    a[3] = (float)inv;
}

__device__ __forceinline__ float2 fmax2(float2 a, float2 b) {
    return make_float2(fmaxf(a.x, b.x), fmaxf(a.y, b.y));
}

// Fused sobel + h-blur + products for 4 output cols (group g) of STH row r.
// NUMERICS CONTRACT (r2, passed): ix = (x02+2*x12+x22)-(x00+2*x10+x20) — the parens are
// column sums cS[c]=w0+2*w1+w2 (same eval order); iy parens are 1,2,1 row sums. Products:
// t=a[d]*ix; xx+=t*ix; xy+=t*iy; yy+=(a[d]*iy)*iy, d ascending. Bit-identical trees.
template<bool CHK>
__device__ __forceinline__ void hblur_fused(const float* SX, float* STH, const float* a,
                                            int r, int g, int x0, int y0) {
    const float* p0 = SX + r * 72 + 4 * g;
    const float* p1 = p0 + 72;
    const float* p2 = p1 + 72;
    float4 A0 = *(const float4*)(p0), B0 = *(const float4*)(p0 + 4), C0 = *(const float4*)(p0 + 8);
    float4 A1 = *(const float4*)(p1), B1 = *(const float4*)(p1 + 4), C1 = *(const float4*)(p1 + 8);
    float4 A2 = *(const float4*)(p2), B2 = *(const float4*)(p2 + 4), C2 = *(const float4*)(p2 + 8);
    float w0[12] = {A0.x, A0.y, A0.z, A0.w, B0.x, B0.y, B0.z, B0.w, C0.x, C0.y, C0.z, C0.w};
    float w1[12] = {A1.x, A1.y, A1.z, A1.w, B1.x, B1.y, B1.z, B1.w, C1.x, C1.y, C1.z, C1.w};
    float w2[12] = {A2.x, A2.y, A2.z, A2.w, B2.x, B2.y, B2.z, B2.w, C2.x, C2.y, C2.z, C2.w};

    float cS[12];
    #pragma unroll
    for (int j = 0; j < 12; ++j) cS[j] = w0[j] + 2.0f * w1[j] + w2[j];
    float ix[10], iy[10];
    #pragma unroll
    for (int j = 0; j < 10; ++j) {
        ix[j] = cS[j + 2] - cS[j];
        float rS2 = w2[j] + 2.0f * w2[j + 1] + w2[j + 2];
        float rS0 = w0[j] + 2.0f * w0[j + 1] + w0[j + 2];
        iy[j] = rS2 - rS0;
        if (CHK) {
            int gy = y0 - 3 + r, gx = x0 - 3 + (4 * g + j);
            if (!((unsigned)gy < (unsigned)IMH && (unsigned)gx < (unsigned)IMW)) {
                ix[j] = 0.f; iy[j] = 0.f;
            }
        }
    }
    float sxx[4], syy[4], sxy[4];
    #pragma unroll
    for (int k = 0; k < 4; ++k) {
        float xx = 0.f, yy = 0.f, xy = 0.f;
        #pragma unroll
        for (int d = 0; d < 7; ++d) {
            float vx = ix[k + d], vy = iy[k + d];
            float t = a[d] * vx;
            xx += t * vx;
            xy += t * vy;
            yy += (a[d] * vy) * vy;
        }
        sxx[k] = xx; syy[k] = yy; sxy[k] = xy;
    }
    *(float4*)&STH[r * 64 + 4 * g]        = make_float4(sxx[0], sxx[1], sxx[2], sxx[3]);
    *(float4*)&STH[2432 + r * 64 + 4 * g] = make_float4(syy[0], syy[1], syy[2], syy[3]);
    *(float4*)&STH[4864 + r * 64 + 4 * g] = make_float4(sxy[0], sxy[1], sxy[2], sxy[3]);
}

// ---------- K1: fused Sobel+products+7x7 Gaussian + R + hist1 (2048 bins) ----------
// tile 64x32, 512 threads. LDS floats (10176 f = 40704 B -> 4 blocks/CU, 32 waves):
//   STH 3 planes f[38][64] @ [0,7296)
//   SX  f[40][72]          @ [7296,10176)  (dead after hblur; LH[2048] aliases)
__launch_bounds__(512, 8)
__global__ void harris_R(const float* __restrict__ x, float* __restrict__ Rout,
                         unsigned* __restrict__ hist) {
    __shared__ __align__(16) float smem[10176];
    float* STH = smem;                       // 3 x [38][64]
    float* SX = smem + 7296;                 // [40][72]
    unsigned* LH = (unsigned*)(smem + 7296); // [2048] aliases dead SX

    const int tid = threadIdx.x;
    const int tx = tid & 63, ty = tid >> 6;
    const int x0 = blockIdx.x * 64, y0 = blockIdx.y * 32, b = blockIdx.z;
    const float* xb = x + (size_t)b * IMH * IMW;
    const bool interior = (x0 >= 4) && (x0 + 68 <= IMW) && (y0 >= 4) && (y0 + 36 <= IMH);

    // ---- stage x tile 40x72 (rows y0-4..y0+35, cols x0-4..x0+67), zero-padded ----
    if (interior) {
        const float* xp = xb + (size_t)(y0 - 4) * IMW + (x0 - 4);
        int r = tid >> 4, k = tid & 15;
        *(float4*)&SX[r * 72 + 4 * k] = *(const float4*)&xp[(size_t)r * IMW + 4 * k];
        if (tid < 128) {
            int r2 = 32 + (tid >> 4);
            *(float4*)&SX[r2 * 72 + 4 * k] = *(const float4*)&xp[(size_t)r2 * IMW + 4 * k];
        }
        if (tid < 80) {
            int r3 = tid >> 1, k3 = 16 + (tid & 1);
            *(float4*)&SX[r3 * 72 + 4 * k3] = *(const float4*)&xp[(size_t)r3 * IMW + 4 * k3];
        }
    } else {
        for (int i = tid; i < 2880; i += 512) {
            int r = i / 72, c = i - r * 72;
            int gy = y0 - 4 + r, gx = x0 - 4 + c;
            float v = 0.f;
            if ((unsigned)gy < (unsigned)IMH && (unsigned)gx < (unsigned)IMW)
                v = xb[(size_t)gy * IMW + gx];
            SX[r * 72 + c] = v;
        }
    }
    __syncthreads();

    float a[7]; gauss7(a);

    // ---- fused sobel + h-blur + products: 38 rows x 16 groups -> planar STH ----
    if (interior) {
        { int r = tid >> 4, g = tid & 15; hblur_fused<false>(SX, STH, a, r, g, x0, y0); }
        if (tid < 96) { int r = 32 + (tid >> 4), g = tid & 15; hblur_fused<false>(SX, STH, a, r, g, x0, y0); }
    } else {
        { int r = tid >> 4, g = tid & 15; hblur_fused<true>(SX, STH, a, r, g, x0, y0); }
        if (tid < 96) { int r = 32 + (tid >> 4), g = tid & 15; hblur_fused<true>(SX, STH, a, r, g, x0, y0); }
    }
    __syncthreads();   // SX dead beyond this point

    // ---- v-blur (reads STH) concurrent with LH zeroing (writes dead-SX region) ----
    for (int i = tid; i < 2048; i += 512) LH[i] = 0u;

    float vxx[10], vyy[10], vxy[10];
    {
        const float* base = STH + (4 * ty) * 64 + tx;
        #pragma unroll
        for (int t = 0; t < 10; ++t) {
            vxx[t] = base[t * 64];
            vyy[t] = base[2432 + t * 64];
            vxy[t] = base[4864 + t * 64];
        }
    }
    float rv[4];
    float* Rb = Rout + (size_t)b * IMH * IMW + (size_t)y0 * IMW + x0;
    #pragma unroll
    for (int j = 0; j < 4; ++j) {
        float sxx = 0.f, syy = 0.f, sxy = 0.f;
        #pragma unroll
        for (int d = 0; d < 7; ++d) {
            sxx += a[d] * vxx[j + d];
            syy += a[d] * vyy[j + d];
            sxy += a[d] * vxy[j + d];
        }
        float tr = sxx + syy;
        float R = sxx * syy - sxy * sxy - 0.05f * tr * tr;
        rv[j] = R;
        Rb[(size_t)(4 * ty + j) * IMW + tx] = R;
    }
    __syncthreads();   // LH zeroed, vblur done

    #pragma unroll
    for (int j = 0; j < 4; ++j) atomicAdd(&LH[f2u(rv[j]) >> 21], 1u);
    __syncthreads();

    const unsigned slot = ((blockIdx.z * gridDim.y + blockIdx.y) * gridDim.x + blockIdx.x) & 7u;
    for (int i = tid; i < 2048; i += 512) {
        unsigned c = LH[i];
        if (c) atomicAdd(&hist[i * 8 + slot], c);
    }
}

// ---------- median: radix select 11+12+9 bits; pass 1 fused above (8-slot) ----------
__global__ void zero_kernel(unsigned* __restrict__ p, int n, int kidx, unsigned kval) {
    int i = blockIdx.x * blockDim.x + threadIdx.x;
    if (i < n) p[i] = (i == kidx) ? kval : 0u;
}

__global__ void hist2_kernel(const float* __restrict__ R, unsigned* __restrict__ hist,
                             const unsigned* __restrict__ sel) {
    __shared__ unsigned lh[4096];
    for (int i = threadIdx.x; i < 4096; i += 256) lh[i] = 0u;
    __syncthreads();
    const unsigned pref = sel[1];
    const float4* R4 = (const float4*)R;
    const int n4 = NPIX / 4;
    for (int i = (blockIdx.x * 256 + threadIdx.x) * 2; i < n4; i += gridDim.x * 512) {
        float4 v0 = R4[i];
        float4 v1 = R4[i + 1];
        unsigned u;
        u = f2u(v0.x); if ((u >> 21) == pref) atomicAdd(&lh[(u >> 9) & 0xFFFu], 1u);
        u = f2u(v0.y); if ((u >> 21) == pref) atomicAdd(&lh[(u >> 9) & 0xFFFu], 1u);
        u = f2u(v0.z); if ((u >> 21) == pref) atomicAdd(&lh[(u >> 9) & 0xFFFu], 1u);
        u = f2u(v0.w); if ((u >> 21) == pref) atomicAdd(&lh[(u >> 9) & 0xFFFu], 1u);
        u = f2u(v1.x); if ((u >> 21) == pref) atomicAdd(&lh[(u >> 9) & 0xFFFu], 1u);
        u = f2u(v1.y); if ((u >> 21) == pref) atomicAdd(&lh[(u >> 9) & 0xFFFu], 1u);
        u = f2u(v1.z); if ((u >> 21) == pref) atomicAdd(&lh[(u >> 9) & 0xFFFu], 1u);
        u = f2u(v1.w); if ((u >> 21) == pref) atomicAdd(&lh[(u >> 9) & 0xFFFu], 1u);
    }
    __syncthreads();
    for (int i = threadIdx.x; i < 4096; i += 256) { unsigned c = lh[i]; if (c) atomicAdd(&hist[i], c); }
}

__global__ void hist3_kernel(const float* __restrict__ R, unsigned* __restrict__ hist,
                             const unsigned* __restrict__ sel) {
    __shared__ unsigned lh[512];
    if (threadIdx.x < 256) { lh[threadIdx.x] = 0u; lh[threadIdx.x + 256] = 0u; }
    __syncthreads();
    const unsigned pref = sel[1];
    const float4* R4 = (const float4*)R;
    const int n4 = NPIX / 4;
    for (int i = (blockIdx.x * 256 + threadIdx.x) * 2; i < n4; i += gridDim.x * 512) {
        float4 v0 = R4[i];
        float4 v1 = R4[i + 1];
        unsigned u;
        u = f2u(v0.x); if ((u >> 9) == pref) atomicAdd(&lh[u & 0x1FFu], 1u);
        u = f2u(v0.y); if ((u >> 9) == pref) atomicAdd(&lh[u & 0x1FFu], 1u);
        u = f2u(v0.z); if ((u >> 9) == pref) atomicAdd(&lh[u & 0x1FFu], 1u);
        u = f2u(v0.w); if ((u >> 9) == pref) atomicAdd(&lh[u & 0x1FFu], 1u);
        u = f2u(v1.x); if ((u >> 9) == pref) atomicAdd(&lh[u & 0x1FFu], 1u);
        u = f2u(v1.y); if ((u >> 9) == pref) atomicAdd(&lh[u & 0x1FFu], 1u);
        u = f2u(v1.z); if ((u >> 9) == pref) atomicAdd(&lh[u & 0x1FFu], 1u);
        u = f2u(v1.w); if ((u >> 9) == pref) atomicAdd(&lh[u & 0x1FFu], 1u);
    }
    __syncthreads();
    if (threadIdx.x < 256) {
        unsigned c = lh[threadIdx.x]; if (c) atomicAdd(&hist[threadIdx.x], c);
        c = lh[threadIdx.x + 256]; if (c) atomicAdd(&hist[threadIdx.x + 256], c);
    }
}

__global__ void select_kernel(const unsigned* __restrict__ hist, unsigned* __restrict__ sel,
                              int bpt, int bits, int final_stage, int slots) {
    __shared__ unsigned part[256];
    __shared__ unsigned grp[16];
    __shared__ int chs;
    __shared__ unsigned runs;
    const int t = threadIdx.x;
    const unsigned krem = sel[0];
    unsigned s = 0;
    for (int i = 0; i < bpt; ++i) {
        unsigned bsum = 0;
        for (int j = 0; j < slots; ++j) bsum += hist[(t * bpt + i) * slots + j];
        s += bsum;
    }
    part[t] = s;
    __syncthreads();
    #pragma unroll
    for (int off = 1; off < 256; off <<= 1) {
        unsigned add = (t >= off) ? part[t - off] : 0u;
        __syncthreads();
        part[t] += add;
        __syncthreads();
    }
    unsigned incl = part[t];
    unsigned excl = incl - s;
    if (excl <= krem && krem < incl) { chs = t; runs = excl; }
    __syncthreads();
    int ch = chs;
    if (t < bpt) {
        unsigned g = 0;
        for (int j = 0; j < slots; ++j) g += hist[(ch * bpt + t) * slots + j];
        grp[t] = g;
    }
    __syncthreads();
    if (t == 0) {
        unsigned r2 = runs; int bsel = ch * bpt;
        for (int j = 0; j < bpt; ++j) {
            unsigned h = grp[j];
            if (r2 + h > krem) { bsel = ch * bpt + j; break; }
            r2 += h;
        }
        sel[0] = krem - r2;
        unsigned pref = (sel[1] << bits) | (unsigned)bsel;
        sel[1] = pref;
        if (final_stage) {
            unsigned fb = (pref & 0x80000000u) ? (pref ^ 0x80000000u) : ~pref;
            ((float*)sel)[2] = __uint_as_float(fb);
        }
    }
}

// ---------- K2: threshold + 7x7 maxpool + binarize*R, tile 64x64, 512 threads ----------
__launch_bounds__(512, 6)
__global__ void harris_out(const float* __restrict__ R, const unsigned* __restrict__ sel,
                           float* __restrict__ out) {
    __shared__ __align__(16) float smem2[9520];   // 38080 B -> 4 blocks/CU
    float* SR = smem2;                            // [70*72] raw R halo 3, OOB=-inf
    float2* SM2 = (float2*)(smem2 + 5040);        // [70*32] horizontal thr-max col pairs
    const float med = ((const float*)sel)[2];
    const int tid = threadIdx.x;
    const int x0 = blockIdx.x * 64, y0 = blockIdx.y * 64, b = blockIdx.z;
    const float* Rb = R + (size_t)b * IMH * IMW;

    for (int i = tid; i < 70 * 70; i += 512) {
        int r = i / 70, c = i - r * 70;
        int gy = y0 - 3 + r, gx = x0 - 3 + c;
        float v = -INFINITY;
        if ((unsigned)gy < (unsigned)IMH && (unsigned)gx < (unsigned)IMW)
            v = Rb[(size_t)gy * IMW + gx];
        SR[r * 72 + c] = v;
    }
    __syncthreads();

    for (int i = tid; i < 70 * 32; i += 512) {
        int r = i >> 5, p = i & 31;
        const float2* u = (const float2*)(SR + r * 72 + 2 * p);
        float2 u0 = u[0], u1 = u[1], u2 = u[2], u3 = u[3];
        float cv[8] = {u0.x, u0.y, u1.x, u1.y, u2.x, u2.y, u3.x, u3.y};
        float tv[8];
        #pragma unroll
        for (int k = 0; k < 8; ++k) {
            float v = cv[k];
            tv[k] = (v < med) ? ((v == -INFINITY) ? -INFINITY : 0.0f) : v;
        }
        float mid = fmaxf(fmaxf(fmaxf(tv[1], tv[2]), fmaxf(tv[3], tv[4])), fmaxf(tv[5], tv[6]));
        SM2[r * 32 + p] = make_float2(fmaxf(tv[0], mid), fmaxf(tv[7], mid));
    }
    __syncthreads();

    const int p = tid & 31, g = tid >> 5;     // g in 0..15
    float2 vm[10];
    #pragma unroll
    for (int t = 0; t < 10; ++t) vm[t] = SM2[(4 * g + t) * 32 + p];
    float2 m2[9];
    #pragma unroll
    for (int i = 0; i < 9; ++i) m2[i] = fmax2(vm[i], vm[i + 1]);
    float2 m4[7];
    #pragma unroll
    for (int i = 0; i < 7; ++i) m4[i] = fmax2(m2[i], m2[i + 2]);
    float* ob = out + (size_t)b * IMH * IMW + (size_t)y0 * IMW + x0;
    #pragma unroll
    for (int j = 0; j < 4; ++j) {
        float2 pooled = fmax2(m4[j], m4[j + 3]);
        float vA = SR[(4 * g + j + 3) * 72 + 2 * p + 3];
        float vB = SR[(4 * g + j + 3) * 72 + 2 * p + 4];
        float tA = (vA < med) ? 0.0f : vA;
        float tB = (vB < med) ? 0.0f : vB;
        float2 o = make_float2((tA == pooled.x) ? vA : 0.0f, (tB == pooled.y) ? vB : 0.0f);
        *(float2*)&ob[(size_t)(4 * g + j) * IMW + 2 * p] = o;
    }
}

extern "C" void kernel_launch(void* const* d_in, const int* in_sizes, int n_in,
                              void* d_out, int out_size, void* d_ws, size_t ws_size,
                              hipStream_t stream) {
    const float* x = (const float*)d_in[0];
    float* out = (float*)d_out;

    // ws: R (64MB) | h1[2048*8] | h2[4096] | h3[512] | sel[8]
    const size_t needed = (size_t)NPIX * 4 + (16384 + 4096 + 512 + 8) * 4;
    if (ws_size < needed) return;
    float* R = (float*)d_ws;
    unsigned* hbase = (unsigned*)((char*)d_ws + (size_t)NPIX * 4);
    unsigned* h1 = hbase;            // 16384 (2048 bins x 8 slots)
    unsigned* h2 = hbase + 16384;    // 4096
    unsigned* h3 = hbase + 20480;    // 512
    unsigned* sel = hbase + 20992;   // 8

    zero_kernel<<<(21000 + 255) / 256, 256, 0, stream>>>(hbase, 21000, 20992, KSEL);

    dim3 rgrid(IMW / 64, IMH / 32, NB);
    harris_R<<<rgrid, 512, 0, stream>>>(x, R, h1);

    select_kernel<<<1, 256, 0, stream>>>(h1, sel, 8, 11, 0, 8);
    hist2_kernel<<<2048, 256, 0, stream>>>(R, h2, sel);
    select_kernel<<<1, 256, 0, stream>>>(h2, sel, 16, 12, 0, 1);
    hist3_kernel<<<2048, 256, 0, stream>>>(R, h3, sel);
    select_kernel<<<1, 256, 0, stream>>>(h3, sel, 2, 9, 1, 1);

    dim3 ogrid(IMW / 64, IMH / 64, NB);
    harris_out<<<ogrid, 512, 0, stream>>>(R, sel, out);
}

// Round 9
// 311.537 us; speedup vs baseline: 1.4221x; 1.4221x over previous
//
#include <hip/hip_runtime.h>
#include <math.h>

constexpr int IMH = 2048, IMW = 2048, NB = 4;
constexpr int NPIX = NB * IMH * IMW;           // 16777216
constexpr unsigned KSEL = 8388607u;            // floor(0.5*(NPIX-1)) -> quantile 'lower'

__device__ __forceinline__ unsigned f2u(float f) {
    unsigned b = __float_as_uint(f);
    return (b & 0x80000000u) ? ~b : (b | 0x80000000u);
}

__device__ __forceinline__ void gauss7(float* a) {
    const double g0 = 0.8352702114112720;   // exp(-0.18)
    const double g1 = 0.9231163463866358;   // exp(-0.08)
    const double g2 = 0.9801986733067553;   // exp(-0.02)
    const double s = 2.0 * (g0 + g1 + g2) + 1.0;
    const double inv = 1.0 / s;
    a[0] = a[6] = (float)(g0 * inv);
    a[1] = a[5] = (float)(g1 * inv);
    a[2] = a[4] = (float)(g2 * inv);
    a[3] = (float)inv;
}

__device__ __forceinline__ float2 fmax2(float2 a, float2 b) {
    return make_float2(fmaxf(a.x, b.x), fmaxf(a.y, b.y));
}

// Fused sobel + h-blur + products for 4 output cols (group g) of STH row r.
// NUMERICS CONTRACT (r8, passed): ix parens = column sums cS=w0+2*w1+w2; iy parens =
// 1,2,1 row sums. Products: t=a[d]*ix; xx+=t*ix; xy+=t*iy; yy+=(a[d]*iy)*iy, d ascending.
template<bool CHK>
__device__ __forceinline__ void hblur_fused(const float* SX, float* STH, const float* a,
                                            int r, int g, int x0, int y0) {
    const float* p0 = SX + r * 72 + 4 * g;
    const float* p1 = p0 + 72;
    const float* p2 = p1 + 72;
    float4 A0 = *(const float4*)(p0), B0 = *(const float4*)(p0 + 4), C0 = *(const float4*)(p0 + 8);
    float4 A1 = *(const float4*)(p1), B1 = *(const float4*)(p1 + 4), C1 = *(const float4*)(p1 + 8);
    float4 A2 = *(const float4*)(p2), B2 = *(const float4*)(p2 + 4), C2 = *(const float4*)(p2 + 8);
    float w0[12] = {A0.x, A0.y, A0.z, A0.w, B0.x, B0.y, B0.z, B0.w, C0.x, C0.y, C0.z, C0.w};
    float w1[12] = {A1.x, A1.y, A1.z, A1.w, B1.x, B1.y, B1.z, B1.w, C1.x, C1.y, C1.z, C1.w};
    float w2[12] = {A2.x, A2.y, A2.z, A2.w, B2.x, B2.y, B2.z, B2.w, C2.x, C2.y, C2.z, C2.w};

    float cS[12];
    #pragma unroll
    for (int j = 0; j < 12; ++j) cS[j] = w0[j] + 2.0f * w1[j] + w2[j];
    float ix[10], iy[10];
    #pragma unroll
    for (int j = 0; j < 10; ++j) {
        ix[j] = cS[j + 2] - cS[j];
        float rS2 = w2[j] + 2.0f * w2[j + 1] + w2[j + 2];
        float rS0 = w0[j] + 2.0f * w0[j + 1] + w0[j + 2];
        iy[j] = rS2 - rS0;
        if (CHK) {
            int gy = y0 - 3 + r, gx = x0 - 3 + (4 * g + j);
            if (!((unsigned)gy < (unsigned)IMH && (unsigned)gx < (unsigned)IMW)) {
                ix[j] = 0.f; iy[j] = 0.f;
            }
        }
    }
    float sxx[4], syy[4], sxy[4];
    #pragma unroll
    for (int k = 0; k < 4; ++k) {
        float xx = 0.f, yy = 0.f, xy = 0.f;
        #pragma unroll
        for (int d = 0; d < 7; ++d) {
            float vx = ix[k + d], vy = iy[k + d];
            float t = a[d] * vx;
            xx += t * vx;
            xy += t * vy;
            yy += (a[d] * vy) * vy;
        }
        sxx[k] = xx; syy[k] = yy; sxy[k] = xy;
    }
    *(float4*)&STH[r * 64 + 4 * g]        = make_float4(sxx[0], sxx[1], sxx[2], sxx[3]);
    *(float4*)&STH[2432 + r * 64 + 4 * g] = make_float4(syy[0], syy[1], syy[2], syy[3]);
    *(float4*)&STH[4864 + r * 64 + 4 * g] = make_float4(sxy[0], sxy[1], sxy[2], sxy[3]);
}

// ---------- K1: fused Sobel+products+7x7 Gaussian + R + hist1 (2048 bins) ----------
// tile 64x32, 256 threads, high-VGPR budget (launch_bounds(256,4) -> cap ~128).
// LDS floats (10176 f = 40704 B <= 40960 -> 4 blocks/CU, 16 waves):
//   STH 3 planes f[38][64] @ [0,7296)
//   SX  f[40][72]          @ [7296,10176)  (dead after hblur; LH[2048] aliases)
__launch_bounds__(256, 4)
__global__ void harris_R(const float* __restrict__ x, float* __restrict__ Rout,
                         unsigned* __restrict__ hist) {
    __shared__ __align__(16) float smem[10176];
    float* STH = smem;                       // 3 x [38][64]
    float* SX = smem + 7296;                 // [40][72]
    unsigned* LH = (unsigned*)(smem + 7296); // [2048] aliases dead SX

    const int tid = threadIdx.x;
    const int tx = tid & 63, ty = tid >> 6;  // ty in 0..3
    const int x0 = blockIdx.x * 64, y0 = blockIdx.y * 32, b = blockIdx.z;
    const float* xb = x + (size_t)b * IMH * IMW;
    const bool interior = (x0 >= 4) && (x0 + 68 <= IMW) && (y0 >= 4) && (y0 + 36 <= IMH);

    // ---- stage x tile 40x72 = 720 float4 (rows y0-4..y0+35, cols x0-4..x0+67) ----
    if (interior) {
        const float* xp = xb + (size_t)(y0 - 4) * IMW + (x0 - 4);
        #pragma unroll
        for (int k = 0; k < 3; ++k) {
            int i = tid + k * 256;
            if (i < 720) {
                int r = i / 18, c4 = i - r * 18;
                *(float4*)&SX[r * 72 + 4 * c4] = *(const float4*)&xp[(size_t)r * IMW + 4 * c4];
            }
        }
    } else {
        for (int i = tid; i < 2880; i += 256) {
            int r = i / 72, c = i - r * 72;
            int gy = y0 - 4 + r, gx = x0 - 4 + c;
            float v = 0.f;
            if ((unsigned)gy < (unsigned)IMH && (unsigned)gx < (unsigned)IMW)
                v = xb[(size_t)gy * IMW + gx];
            SX[r * 72 + c] = v;
        }
    }
    __syncthreads();

    float a[7]; gauss7(a);

    // ---- fused sobel + h-blur + products: 38 rows x 16 groups = 608 tasks ----
    if (interior) {
        #pragma unroll
        for (int k = 0; k < 3; ++k) {
            int i = tid + k * 256;
            if (i < 608) { int r = i >> 4, g = i & 15; hblur_fused<false>(SX, STH, a, r, g, x0, y0); }
        }
    } else {
        #pragma unroll
        for (int k = 0; k < 3; ++k) {
            int i = tid + k * 256;
            if (i < 608) { int r = i >> 4, g = i & 15; hblur_fused<true>(SX, STH, a, r, g, x0, y0); }
        }
    }
    __syncthreads();   // SX dead beyond this point

    // ---- v-blur (reads STH) concurrent with LH zeroing (writes dead-SX region) ----
    for (int i = tid; i < 2048; i += 256) LH[i] = 0u;

    // 8 consecutive rows/thread; 14-row x 3ch window; per-output d ascending (r2 tree)
    float vxx[14], vyy[14], vxy[14];
    {
        const float* base = STH + (8 * ty) * 64 + tx;
        #pragma unroll
        for (int t = 0; t < 14; ++t) {
            vxx[t] = base[t * 64];
            vyy[t] = base[2432 + t * 64];
            vxy[t] = base[4864 + t * 64];
        }
    }
    float rv[8];
    float* Rb = Rout + (size_t)b * IMH * IMW + (size_t)y0 * IMW + x0;
    #pragma unroll
    for (int j = 0; j < 8; ++j) {
        float sxx = 0.f, syy = 0.f, sxy = 0.f;
        #pragma unroll
        for (int d = 0; d < 7; ++d) {
            sxx += a[d] * vxx[j + d];
            syy += a[d] * vyy[j + d];
            sxy += a[d] * vxy[j + d];
        }
        float tr = sxx + syy;
        float R = sxx * syy - sxy * sxy - 0.05f * tr * tr;
        rv[j] = R;
        Rb[(size_t)(8 * ty + j) * IMW + tx] = R;
    }
    __syncthreads();   // LH zeroed, vblur done

    #pragma unroll
    for (int j = 0; j < 8; ++j) atomicAdd(&LH[f2u(rv[j]) >> 21], 1u);
    __syncthreads();

    const unsigned slot = ((blockIdx.z * gridDim.y + blockIdx.y) * gridDim.x + blockIdx.x) & 7u;
    for (int i = tid; i < 2048; i += 256) {
        unsigned c = LH[i];
        if (c) atomicAdd(&hist[i * 8 + slot], c);
    }
}

// ---------- median: radix select 11+12+9 bits; pass 1 fused above (8-slot) ----------
__global__ void zero_kernel(unsigned* __restrict__ p, int n, int kidx, unsigned kval) {
    int i = blockIdx.x * blockDim.x + threadIdx.x;
    if (i < n) p[i] = (i == kidx) ? kval : 0u;
}

__global__ void hist2_kernel(const float* __restrict__ R, unsigned* __restrict__ hist,
                             const unsigned* __restrict__ sel) {
    __shared__ unsigned lh[4096];
    for (int i = threadIdx.x; i < 4096; i += 256) lh[i] = 0u;
    __syncthreads();
    const unsigned pref = sel[1];
    const float4* R4 = (const float4*)R;
    const int n4 = NPIX / 4;
    for (int i = (blockIdx.x * 256 + threadIdx.x) * 2; i < n4; i += gridDim.x * 512) {
        float4 v0 = R4[i];
        float4 v1 = R4[i + 1];
        unsigned u;
        u = f2u(v0.x); if ((u >> 21) == pref) atomicAdd(&lh[(u >> 9) & 0xFFFu], 1u);
        u = f2u(v0.y); if ((u >> 21) == pref) atomicAdd(&lh[(u >> 9) & 0xFFFu], 1u);
        u = f2u(v0.z); if ((u >> 21) == pref) atomicAdd(&lh[(u >> 9) & 0xFFFu], 1u);
        u = f2u(v0.w); if ((u >> 21) == pref) atomicAdd(&lh[(u >> 9) & 0xFFFu], 1u);
        u = f2u(v1.x); if ((u >> 21) == pref) atomicAdd(&lh[(u >> 9) & 0xFFFu], 1u);
        u = f2u(v1.y); if ((u >> 21) == pref) atomicAdd(&lh[(u >> 9) & 0xFFFu], 1u);
        u = f2u(v1.z); if ((u >> 21) == pref) atomicAdd(&lh[(u >> 9) & 0xFFFu], 1u);
        u = f2u(v1.w); if ((u >> 21) == pref) atomicAdd(&lh[(u >> 9) & 0xFFFu], 1u);
    }
    __syncthreads();
    for (int i = threadIdx.x; i < 4096; i += 256) { unsigned c = lh[i]; if (c) atomicAdd(&hist[i], c); }
}

__global__ void hist3_kernel(const float* __restrict__ R, unsigned* __restrict__ hist,
                             const unsigned* __restrict__ sel) {
    __shared__ unsigned lh[512];
    if (threadIdx.x < 256) { lh[threadIdx.x] = 0u; lh[threadIdx.x + 256] = 0u; }
    __syncthreads();
    const unsigned pref = sel[1];
    const float4* R4 = (const float4*)R;
    const int n4 = NPIX / 4;
    for (int i = (blockIdx.x * 256 + threadIdx.x) * 2; i < n4; i += gridDim.x * 512) {
        float4 v0 = R4[i];
        float4 v1 = R4[i + 1];
        unsigned u;
        u = f2u(v0.x); if ((u >> 9) == pref) atomicAdd(&lh[u & 0x1FFu], 1u);
        u = f2u(v0.y); if ((u >> 9) == pref) atomicAdd(&lh[u & 0x1FFu], 1u);
        u = f2u(v0.z); if ((u >> 9) == pref) atomicAdd(&lh[u & 0x1FFu], 1u);
        u = f2u(v0.w); if ((u >> 9) == pref) atomicAdd(&lh[u & 0x1FFu], 1u);
        u = f2u(v1.x); if ((u >> 9) == pref) atomicAdd(&lh[u & 0x1FFu], 1u);
        u = f2u(v1.y); if ((u >> 9) == pref) atomicAdd(&lh[u & 0x1FFu], 1u);
        u = f2u(v1.z); if ((u >> 9) == pref) atomicAdd(&lh[u & 0x1FFu], 1u);
        u = f2u(v1.w); if ((u >> 9) == pref) atomicAdd(&lh[u & 0x1FFu], 1u);
    }
    __syncthreads();
    if (threadIdx.x < 256) {
        unsigned c = lh[threadIdx.x]; if (c) atomicAdd(&hist[threadIdx.x], c);
        c = lh[threadIdx.x + 256]; if (c) atomicAdd(&hist[threadIdx.x + 256], c);
    }
}

__global__ void select_kernel(const unsigned* __restrict__ hist, unsigned* __restrict__ sel,
                              int bpt, int bits, int final_stage, int slots) {
    __shared__ unsigned part[256];
    __shared__ unsigned grp[16];
    __shared__ int chs;
    __shared__ unsigned runs;
    const int t = threadIdx.x;
    const unsigned krem = sel[0];
    unsigned s = 0;
    for (int i = 0; i < bpt; ++i) {
        unsigned bsum = 0;
        for (int j = 0; j < slots; ++j) bsum += hist[(t * bpt + i) * slots + j];
        s += bsum;
    }
    part[t] = s;
    __syncthreads();
    #pragma unroll
    for (int off = 1; off < 256; off <<= 1) {
        unsigned add = (t >= off) ? part[t - off] : 0u;
        __syncthreads();
        part[t] += add;
        __syncthreads();
    }
    unsigned incl = part[t];
    unsigned excl = incl - s;
    if (excl <= krem && krem < incl) { chs = t; runs = excl; }
    __syncthreads();
    int ch = chs;
    if (t < bpt) {
        unsigned g = 0;
        for (int j = 0; j < slots; ++j) g += hist[(ch * bpt + t) * slots + j];
        grp[t] = g;
    }
    __syncthreads();
    if (t == 0) {
        unsigned r2 = runs; int bsel = ch * bpt;
        for (int j = 0; j < bpt; ++j) {
            unsigned h = grp[j];
            if (r2 + h > krem) { bsel = ch * bpt + j; break; }
            r2 += h;
        }
        sel[0] = krem - r2;
        unsigned pref = (sel[1] << bits) | (unsigned)bsel;
        sel[1] = pref;
        if (final_stage) {
            unsigned fb = (pref & 0x80000000u) ? (pref ^ 0x80000000u) : ~pref;
            ((float*)sel)[2] = __uint_as_float(fb);
        }
    }
}

// ---------- K2: threshold + 7x7 maxpool + binarize*R, tile 64x64, 512 threads ----------
__launch_bounds__(512, 6)
__global__ void harris_out(const float* __restrict__ R, const unsigned* __restrict__ sel,
                           float* __restrict__ out) {
    __shared__ __align__(16) float smem2[9520];   // 38080 B -> 4 blocks/CU
    float* SR = smem2;                            // [70*72] raw R halo 3, OOB=-inf
    float2* SM2 = (float2*)(smem2 + 5040);        // [70*32] horizontal thr-max col pairs
    const float med = ((const float*)sel)[2];
    const int tid = threadIdx.x;
    const int x0 = blockIdx.x * 64, y0 = blockIdx.y * 64, b = blockIdx.z;
    const float* Rb = R + (size_t)b * IMH * IMW;

    for (int i = tid; i < 70 * 70; i += 512) {
        int r = i / 70, c = i - r * 70;
        int gy = y0 - 3 + r, gx = x0 - 3 + c;
        float v = -INFINITY;
        if ((unsigned)gy < (unsigned)IMH && (unsigned)gx < (unsigned)IMW)
            v = Rb[(size_t)gy * IMW + gx];
        SR[r * 72 + c] = v;
    }
    __syncthreads();

    for (int i = tid; i < 70 * 32; i += 512) {
        int r = i >> 5, p = i & 31;
        const float2* u = (const float2*)(SR + r * 72 + 2 * p);
        float2 u0 = u[0], u1 = u[1], u2 = u[2], u3 = u[3];
        float cv[8] = {u0.x, u0.y, u1.x, u1.y, u2.x, u2.y, u3.x, u3.y};
        float tv[8];
        #pragma unroll
        for (int k = 0; k < 8; ++k) {
            float v = cv[k];
            tv[k] = (v < med) ? ((v == -INFINITY) ? -INFINITY : 0.0f) : v;
        }
        float mid = fmaxf(fmaxf(fmaxf(tv[1], tv[2]), fmaxf(tv[3], tv[4])), fmaxf(tv[5], tv[6]));
        SM2[r * 32 + p] = make_float2(fmaxf(tv[0], mid), fmaxf(tv[7], mid));
    }
    __syncthreads();

    const int p = tid & 31, g = tid >> 5;     // g in 0..15
    float2 vm[10];
    #pragma unroll
    for (int t = 0; t < 10; ++t) vm[t] = SM2[(4 * g + t) * 32 + p];
    float2 m2[9];
    #pragma unroll
    for (int i = 0; i < 9; ++i) m2[i] = fmax2(vm[i], vm[i + 1]);
    float2 m4[7];
    #pragma unroll
    for (int i = 0; i < 7; ++i) m4[i] = fmax2(m2[i], m2[i + 2]);
    float* ob = out + (size_t)b * IMH * IMW + (size_t)y0 * IMW + x0;
    #pragma unroll
    for (int j = 0; j < 4; ++j) {
        float2 pooled = fmax2(m4[j], m4[j + 3]);
        float vA = SR[(4 * g + j + 3) * 72 + 2 * p + 3];
        float vB = SR[(4 * g + j + 3) * 72 + 2 * p + 4];
        float tA = (vA < med) ? 0.0f : vA;
        float tB = (vB < med) ? 0.0f : vB;
        float2 o = make_float2((tA == pooled.x) ? vA : 0.0f, (tB == pooled.y) ? vB : 0.0f);
        *(float2*)&ob[(size_t)(4 * g + j) * IMW + 2 * p] = o;
    }
}

extern "C" void kernel_launch(void* const* d_in, const int* in_sizes, int n_in,
                              void* d_out, int out_size, void* d_ws, size_t ws_size,
                              hipStream_t stream) {
    const float* x = (const float*)d_in[0];
    float* out = (float*)d_out;

    // ws: R (64MB) | h1[2048*8] | h2[4096] | h3[512] | sel[8]
    const size_t needed = (size_t)NPIX * 4 + (16384 + 4096 + 512 + 8) * 4;
    if (ws_size < needed) return;
    float* R = (float*)d_ws;
    unsigned* hbase = (unsigned*)((char*)d_ws + (size_t)NPIX * 4);
    unsigned* h1 = hbase;            // 16384 (2048 bins x 8 slots)
    unsigned* h2 = hbase + 16384;    // 4096
    unsigned* h3 = hbase + 20480;    // 512
    unsigned* sel = hbase + 20992;   // 8

    zero_kernel<<<(21000 + 255) / 256, 256, 0, stream>>>(hbase, 21000, 20992, KSEL);

    dim3 rgrid(IMW / 64, IMH / 32, NB);
    harris_R<<<rgrid, 256, 0, stream>>>(x, R, h1);

    select_kernel<<<1, 256, 0, stream>>>(h1, sel, 8, 11, 0, 8);
    hist2_kernel<<<2048, 256, 0, stream>>>(R, h2, sel);
    select_kernel<<<1, 256, 0, stream>>>(h2, sel, 16, 12, 0, 1);
    hist3_kernel<<<2048, 256, 0, stream>>>(R, h3, sel);
    select_kernel<<<1, 256, 0, stream>>>(h3, sel, 2, 9, 1, 1);

    dim3 ogrid(IMW / 64, IMH / 64, NB);
    harris_out<<<ogrid, 512, 0, stream>>>(R, sel, out);
}